// Round 7
// baseline (677.886 us; speedup 1.0000x reference)
//
#include <hip/hip_runtime.h>

#define AB 513
#define TD 263169  // 513*513

typedef float f4 __attribute__((ext_vector_type(4)));
typedef int v8i __attribute__((ext_vector_type(8)));
#define GAS __attribute__((address_space(1)))
#define LAS __attribute__((address_space(3)))

// ---------------------------------------------------------------------------
// Kernel 1: both modalities. Blocks 0..63 = vision bt, 64..127 = audio bt.
// ---------------------------------------------------------------------------
__global__ __launch_bounds__(256) void unimodal_kernel(
    const float* __restrict__ vx, const float* __restrict__ ax,
    const float* __restrict__ vw1, const float* __restrict__ vb1,
    const float* __restrict__ vw2, const float* __restrict__ vb2,
    const float* __restrict__ aw1, const float* __restrict__ ab1,
    const float* __restrict__ aw2, const float* __restrict__ ab2,
    float* __restrict__ aTout, float* __restrict__ bTout)
{
    const int isA = (blockIdx.x >= 64);
    const int bt = blockIdx.x & 63;
    const float* x  = isA ? ax  : vx;
    const float* w1 = isA ? aw1 : vw1;
    const float* b1 = isA ? ab1 : vb1;
    const float* w2 = isA ? aw2 : vw2;
    const float* b2 = isA ? ab2 : vb2;
    float* outT = isA ? bTout : aTout;
    const int D = isA ? 512 : 768;

    __shared__ float p_sh[768];
    __shared__ float h_sh[512];
    const int tid = threadIdx.x;
    const int lane = tid & 63, wid = tid >> 6;

    const int nd4 = D >> 2;
    for (int d4 = tid; d4 < nd4; d4 += 256) {
        f4 s0 = {0.f, 0.f, 0.f, 0.f}, s1 = s0, s2 = s0, s3 = s0;
        const float* xp = x + (size_t)bt * 64 * D + d4 * 4;
        #pragma unroll 4
        for (int ss = 0; ss < 64; ss += 4) {
            s0 += *(const f4*)(xp + (size_t)ss * D);
            s1 += *(const f4*)(xp + (size_t)(ss + 1) * D);
            s2 += *(const f4*)(xp + (size_t)(ss + 2) * D);
            s3 += *(const f4*)(xp + (size_t)(ss + 3) * D);
        }
        const f4 s = (s0 + s1) + (s2 + s3);
        *(f4*)&p_sh[d4 * 4] = s * 0.015625f;
    }
    __syncthreads();

    const int nit = D >> 8;
    for (int h0 = wid * 8; h0 < 512; h0 += 32) {
        float s[8];
        #pragma unroll
        for (int k = 0; k < 8; ++k) s[k] = 0.f;
        for (int it = 0; it < nit; ++it) {
            const int d = it * 256 + lane * 4;
            const f4 p = *(const f4*)&p_sh[d];
            #pragma unroll
            for (int k = 0; k < 8; ++k) {
                const f4 w = *(const f4*)&w1[(size_t)(h0 + k) * D + d];
                s[k] = fmaf(w[0], p[0], fmaf(w[1], p[1],
                       fmaf(w[2], p[2], fmaf(w[3], p[3], s[k]))));
            }
        }
        #pragma unroll
        for (int k = 0; k < 8; ++k) {
            float v = s[k];
            #pragma unroll
            for (int m = 1; m < 64; m <<= 1) v += __shfl_xor(v, m, 64);
            if (lane == 0) h_sh[h0 + k] = fmaxf(v + b1[h0 + k], 0.f);
        }
    }
    __syncthreads();

    for (int h0 = wid * 8; h0 < 512; h0 += 32) {
        float s[8];
        #pragma unroll
        for (int k = 0; k < 8; ++k) s[k] = 0.f;
        for (int it = 0; it < 2; ++it) {
            const int d = it * 256 + lane * 4;
            const f4 p = *(const f4*)&h_sh[d];
            #pragma unroll
            for (int k = 0; k < 8; ++k) {
                const f4 w = *(const f4*)&w2[(size_t)(h0 + k) * 512 + d];
                s[k] = fmaf(w[0], p[0], fmaf(w[1], p[1],
                       fmaf(w[2], p[2], fmaf(w[3], p[3], s[k]))));
            }
        }
        #pragma unroll
        for (int k = 0; k < 8; ++k) {
            float v = s[k];
            #pragma unroll
            for (int m = 1; m < 64; m <<= 1) v += __shfl_xor(v, m, 64);
            if (lane == 0) outT[(h0 + k) * 64 + bt] = v + b2[h0 + k];
        }
    }
    if (tid == 0) outT[512 * 64 + bt] = 1.0f;
}

// ---------------------------------------------------------------------------
// Kernel 2: bilinear h[bt,o] = relu( a^T W_o b + fb1[o] ).
// Grid 1024 x 512 thr; one block per o. Wave = bt-octet; thread e-set
// {4*lane..+3} U {256+4*lane..+3}; acc[8e][8bt] in VGPRs.
// W: 4-deep LDS ring, async global_load_lds width-16, staged AFTER the
// barrier (3 chunks in flight, counted vmcnt(4), never 0).
// a: SMEM path — 8 x s_load_dwordx8 per chunk per wave (wave-uniform addr,
// scalar cache), trailing lgkmcnt(0) inside the asm keeps the compiler's
// waitcnt model conservative-correct. FMAs: v_fma(v_w, s_a, v_acc).
// Race proof: post-barrier STAGE writes buf (c+3)&3; slowest reader is in
// epoch c on buf c&3; collision would need 3==0 (mod 4) -> none. The only
// other candidate (c-1)&3 is protected by the barrier just passed.
// ---------------------------------------------------------------------------
__global__ __launch_bounds__(512, 2) void bilinear_kernel(
    const float* __restrict__ fw1,  // (1024, 263169)
    const float* __restrict__ fb1,  // (1024)
    const float* __restrict__ aT,   // (513, 64)
    const float* __restrict__ bT,   // (513, 64)
    float* __restrict__ hbuf)       // (64, 1024)
{
    __shared__ float wbuf[4][8 * 512];  // 64 KB
    const int tid = threadIdx.x;
    const int lane = tid & 63, w = tid >> 6;
    const int o = blockIdx.x;
    const float* __restrict__ W = fw1 + (size_t)o * TD;
    const int e0 = lane * 4;   // quads at e0 and e0+256
    const int bt0 = w * 8;
    const int bt0r = __builtin_amdgcn_readfirstlane(bt0);

    // W chunk stage: 8 rows x 512 floats, width-16, 2 instrs/thread.
    const int srow = tid >> 7, scol = (tid & 127) * 4;
    #define STAGE(buf_, c_)                                                    \
        do {                                                                   \
            _Pragma("unroll")                                                  \
            for (int s_ = 0; s_ < 2; ++s_) {                                   \
                const int r_ = s_ * 4 + srow;                                  \
                __builtin_amdgcn_global_load_lds(                              \
                    (const GAS uint32_t*)(const void*)(W + (size_t)(c_) * 8 * AB + (size_t)r_ * AB + scol), \
                    (LAS uint32_t*)(void*)&wbuf[buf_][r_ * 512 + scol], 16, 0, 0); \
            }                                                                  \
        } while (0)

    // one dd-step: 2 x ds_read_b128 (W) + 8 FMA-quads with SGPR a-operand
    #define DDSTEP(dd_, q_)                                                    \
        do {                                                                   \
            const f4 w0  = *(const f4*)&wb[(dd_) * 512 + e0];                  \
            const f4 w1v = *(const f4*)&wb[(dd_) * 512 + e0 + 256];            \
            _Pragma("unroll")                                                  \
            for (int j = 0; j < 8; ++j) {                                      \
                const float av = __int_as_float(q_[j]);                        \
                _Pragma("unroll")                                              \
                for (int i = 0; i < 4; ++i) {                                  \
                    acc[i][j]     = fmaf(w0[i],  av, acc[i][j]);               \
                    acc[i + 4][j] = fmaf(w1v[i], av, acc[i + 4][j]);           \
                }                                                              \
            }                                                                  \
        } while (0)

    float acc[8][8];  // [e-sub][bt]
    #pragma unroll
    for (int i = 0; i < 8; ++i)
        #pragma unroll
        for (int j = 0; j < 8; ++j) acc[i][j] = 0.f;

    STAGE(0, 0);
    STAGE(1, 1);
    STAGE(2, 2);

    #pragma unroll 1
    for (int c = 0; c < 64; ++c) {
        asm volatile("s_waitcnt vmcnt(4)" ::: "memory");
        __builtin_amdgcn_s_barrier();
        STAGE((c + 3) & 3, (c + 3) & 63);  // wrap chunks 0..2: redundant, safe

        // a-octets for this chunk: 8 rows x 8 bt, wave-uniform -> SMEM
        const float* ap = aT + (size_t)c * 512 + bt0r;
        v8i q0, q1, q2, q3, q4, q5, q6, q7;
        asm volatile(
            "s_load_dwordx8 %0, %8, 0x0\n\t"
            "s_load_dwordx8 %1, %8, 0x100\n\t"
            "s_load_dwordx8 %2, %8, 0x200\n\t"
            "s_load_dwordx8 %3, %8, 0x300\n\t"
            "s_load_dwordx8 %4, %8, 0x400\n\t"
            "s_load_dwordx8 %5, %8, 0x500\n\t"
            "s_load_dwordx8 %6, %8, 0x600\n\t"
            "s_load_dwordx8 %7, %8, 0x700\n\t"
            "s_waitcnt lgkmcnt(0)"
            : "=s"(q0), "=s"(q1), "=s"(q2), "=s"(q3),
              "=s"(q4), "=s"(q5), "=s"(q6), "=s"(q7)
            : "s"(ap));

        const float* __restrict__ wb = wbuf[c & 3];
        DDSTEP(0, q0); DDSTEP(1, q1); DDSTEP(2, q2); DDSTEP(3, q3);
        DDSTEP(4, q4); DDSTEP(5, q5); DDSTEP(6, q6); DDSTEP(7, q7);
    }

    // d = 512 row (a == 1): acc[i][*] += W[512, e_i]
    {
        const f4 r0 = *(const f4*)(W + (size_t)512 * AB + e0);
        const f4 r1 = *(const f4*)(W + (size_t)512 * AB + e0 + 256);
        #pragma unroll
        for (int j = 0; j < 8; ++j)
            #pragma unroll
            for (int i = 0; i < 4; ++i) {
                acc[i][j] += r0[i];
                acc[i + 4][j] += r1[i];
            }
    }

    // y[j] = sum over this thread's e of acc * b[e, bt0+j]
    float y[8];
    #pragma unroll
    for (int j = 0; j < 8; ++j) y[j] = 0.f;
    #pragma unroll
    for (int i = 0; i < 4; ++i) {
        const float* br0 = bT + (size_t)(e0 + i) * 64 + bt0;
        const float* br1 = bT + (size_t)(256 + e0 + i) * 64 + bt0;
        const f4 b0a = *(const f4*)br0, b0b = *(const f4*)(br0 + 4);
        const f4 b1a = *(const f4*)br1, b1b = *(const f4*)(br1 + 4);
        #pragma unroll
        for (int j = 0; j < 4; ++j) {
            y[j]     = fmaf(acc[i][j],     b0a[j], y[j]);
            y[j]     = fmaf(acc[i + 4][j], b1a[j], y[j]);
            y[j + 4] = fmaf(acc[i][j + 4],     b0b[j], y[j + 4]);
            y[j + 4] = fmaf(acc[i + 4][j + 4], b1b[j], y[j + 4]);
        }
    }

    // e = 512 column (b == 1): y[j] += sum_d a[d, bt0+j] * W[d, 512]
    #pragma unroll
    for (int k = 0; k < 8; ++k) {
        const int d = k * 64 + lane;
        const float wv = W[(size_t)d * AB + 512];
        const float* ar = aT + (size_t)d * 64 + bt0;
        const f4 a0 = *(const f4*)ar, a1 = *(const f4*)(ar + 4);
        #pragma unroll
        for (int j = 0; j < 4; ++j) {
            y[j]     = fmaf(a0[j], wv, y[j]);
            y[j + 4] = fmaf(a1[j], wv, y[j + 4]);
        }
    }
    {   // d = 512, e = 512 corner (a = b = 1), add on lane 0 only
        const float wc = (lane == 0) ? W[(size_t)512 * AB + 512] : 0.f;
        #pragma unroll
        for (int j = 0; j < 8; ++j) y[j] += wc;
    }

    // reduce across 64 lanes (all e), then bias + relu + store (per-wave)
    #pragma unroll
    for (int j = 0; j < 8; ++j) {
        float v = y[j];
        #pragma unroll
        for (int m = 1; m < 64; m <<= 1) v += __shfl_xor(v, m, 64);
        y[j] = v;
    }
    if (lane == 0) {
        const float bias = fb1[o];
        #pragma unroll
        for (int j = 0; j < 8; ++j)
            hbuf[(size_t)(bt0 + j) * 1024 + o] = fmaxf(y[j] + bias, 0.f);
    }
    #undef STAGE
    #undef DDSTEP
}

// ---------------------------------------------------------------------------
// Kernel 3a: fused[bt, f] = h[bt, :] @ fw2[f, :] + fb2[f]
// ---------------------------------------------------------------------------
__global__ __launch_bounds__(256) void fuse2_kernel(
    const float* __restrict__ hbuf,  // (64, 1024)
    const float* __restrict__ fw2,   // (512, 1024)
    const float* __restrict__ fb2,   // (512)
    float* __restrict__ fused)       // (64, 512)
{
    __shared__ float h_sh[1024];
    const int bt = blockIdx.x, tid = threadIdx.x;
    const int lane = tid & 63, wid = tid >> 6;
    *(f4*)&h_sh[tid * 4] = *(const f4*)&hbuf[bt * 1024 + tid * 4];
    __syncthreads();
    for (int f0 = wid * 8; f0 < 512; f0 += 32) {
        float s[8];
        #pragma unroll
        for (int k = 0; k < 8; ++k) s[k] = 0.f;
        #pragma unroll
        for (int it = 0; it < 4; ++it) {
            const int d = it * 256 + lane * 4;
            const f4 p = *(const f4*)&h_sh[d];
            #pragma unroll
            for (int k = 0; k < 8; ++k) {
                const f4 w = *(const f4*)&fw2[(size_t)(f0 + k) * 1024 + d];
                s[k] = fmaf(w[0], p[0], fmaf(w[1], p[1],
                       fmaf(w[2], p[2], fmaf(w[3], p[3], s[k]))));
            }
        }
        #pragma unroll
        for (int k = 0; k < 8; ++k) {
            float v = s[k];
            #pragma unroll
            for (int m = 1; m < 64; m <<= 1) v += __shfl_xor(v, m, 64);
            if (lane == 0) fused[bt * 512 + f0 + k] = v + fb2[f0 + k];
        }
    }
}

// ---------------------------------------------------------------------------
// Kernel 3b: LIF over time. 1024 independent (b, d) chains, T = 32.
// ---------------------------------------------------------------------------
__global__ __launch_bounds__(256) void lif_kernel(
    const float* __restrict__ fused,  // (2, 32, 512)
    float* __restrict__ out)          // (2, 32, 512)
{
    const int idx = blockIdx.x * 256 + threadIdx.x;
    if (idx >= 1024) return;
    const int b = idx >> 9, dd = idx & 511;
    float mem = 0.f;
    for (int t = 0; t < 32; ++t) {
        const size_t off = ((size_t)(b * 32 + t) * 512) + dd;
        mem = 0.9f * mem + fused[off];
        const float s = (mem >= 1.0f) ? 1.0f : 0.0f;
        out[off] = s;
        mem -= s;
    }
}

// ---------------------------------------------------------------------------
extern "C" void kernel_launch(void* const* d_in, const int* in_sizes, int n_in,
                              void* d_out, int out_size, void* d_ws, size_t ws_size,
                              hipStream_t stream) {
    const float* vision = (const float*)d_in[0];
    const float* audio  = (const float*)d_in[1];
    const float* vw1 = (const float*)d_in[2];
    const float* vb1 = (const float*)d_in[3];
    const float* vw2 = (const float*)d_in[4];
    const float* vb2 = (const float*)d_in[5];
    const float* aw1 = (const float*)d_in[6];
    const float* ab1 = (const float*)d_in[7];
    const float* aw2 = (const float*)d_in[8];
    const float* ab2 = (const float*)d_in[9];
    const float* fw1 = (const float*)d_in[10];
    const float* fb1 = (const float*)d_in[11];
    const float* fw2 = (const float*)d_in[12];
    const float* fb2 = (const float*)d_in[13];
    float* out = (float*)d_out;

    float* ws    = (float*)d_ws;
    float* aT    = ws;                 // 513*64
    float* bT    = aT + AB * 64;       // 513*64
    float* hbuf  = bT + AB * 64;       // 64*1024
    float* fused = hbuf + 64 * 1024;   // 64*512

    unimodal_kernel<<<128, 256, 0, stream>>>(vision, audio,
        vw1, vb1, vw2, vb2, aw1, ab1, aw2, ab2, aT, bT);
    bilinear_kernel<<<1024, 512, 0, stream>>>(fw1, fb1, aT, bT, hbuf);
    fuse2_kernel<<<64, 256, 0, stream>>>(hbuf, fw2, fb2, fused);
    lif_kernel<<<4, 256, 0, stream>>>(fused, out);
}

// Round 8
// 582.256 us; speedup vs baseline: 1.1642x; 1.1642x over previous
//
#include <hip/hip_runtime.h>

#define AB 513
#define TD 263169  // 513*513

typedef float f4 __attribute__((ext_vector_type(4)));
#define GAS __attribute__((address_space(1)))
#define LAS __attribute__((address_space(3)))

// ---------------------------------------------------------------------------
// Kernel 1: both modalities. Blocks 0..63 = vision bt, 64..127 = audio bt.
// ---------------------------------------------------------------------------
__global__ __launch_bounds__(256) void unimodal_kernel(
    const float* __restrict__ vx, const float* __restrict__ ax,
    const float* __restrict__ vw1, const float* __restrict__ vb1,
    const float* __restrict__ vw2, const float* __restrict__ vb2,
    const float* __restrict__ aw1, const float* __restrict__ ab1,
    const float* __restrict__ aw2, const float* __restrict__ ab2,
    float* __restrict__ aTout, float* __restrict__ bTout)
{
    const int isA = (blockIdx.x >= 64);
    const int bt = blockIdx.x & 63;
    const float* x  = isA ? ax  : vx;
    const float* w1 = isA ? aw1 : vw1;
    const float* b1 = isA ? ab1 : vb1;
    const float* w2 = isA ? aw2 : vw2;
    const float* b2 = isA ? ab2 : vb2;
    float* outT = isA ? bTout : aTout;
    const int D = isA ? 512 : 768;

    __shared__ float p_sh[768];
    __shared__ float h_sh[512];
    const int tid = threadIdx.x;
    const int lane = tid & 63, wid = tid >> 6;

    const int nd4 = D >> 2;
    for (int d4 = tid; d4 < nd4; d4 += 256) {
        f4 s0 = {0.f, 0.f, 0.f, 0.f}, s1 = s0, s2 = s0, s3 = s0;
        const float* xp = x + (size_t)bt * 64 * D + d4 * 4;
        #pragma unroll 4
        for (int ss = 0; ss < 64; ss += 4) {
            s0 += *(const f4*)(xp + (size_t)ss * D);
            s1 += *(const f4*)(xp + (size_t)(ss + 1) * D);
            s2 += *(const f4*)(xp + (size_t)(ss + 2) * D);
            s3 += *(const f4*)(xp + (size_t)(ss + 3) * D);
        }
        const f4 s = (s0 + s1) + (s2 + s3);
        *(f4*)&p_sh[d4 * 4] = s * 0.015625f;
    }
    __syncthreads();

    const int nit = D >> 8;
    for (int h0 = wid * 8; h0 < 512; h0 += 32) {
        float s[8];
        #pragma unroll
        for (int k = 0; k < 8; ++k) s[k] = 0.f;
        for (int it = 0; it < nit; ++it) {
            const int d = it * 256 + lane * 4;
            const f4 p = *(const f4*)&p_sh[d];
            #pragma unroll
            for (int k = 0; k < 8; ++k) {
                const f4 w = *(const f4*)&w1[(size_t)(h0 + k) * D + d];
                s[k] = fmaf(w[0], p[0], fmaf(w[1], p[1],
                       fmaf(w[2], p[2], fmaf(w[3], p[3], s[k]))));
            }
        }
        #pragma unroll
        for (int k = 0; k < 8; ++k) {
            float v = s[k];
            #pragma unroll
            for (int m = 1; m < 64; m <<= 1) v += __shfl_xor(v, m, 64);
            if (lane == 0) h_sh[h0 + k] = fmaxf(v + b1[h0 + k], 0.f);
        }
    }
    __syncthreads();

    for (int h0 = wid * 8; h0 < 512; h0 += 32) {
        float s[8];
        #pragma unroll
        for (int k = 0; k < 8; ++k) s[k] = 0.f;
        for (int it = 0; it < 2; ++it) {
            const int d = it * 256 + lane * 4;
            const f4 p = *(const f4*)&h_sh[d];
            #pragma unroll
            for (int k = 0; k < 8; ++k) {
                const f4 w = *(const f4*)&w2[(size_t)(h0 + k) * 512 + d];
                s[k] = fmaf(w[0], p[0], fmaf(w[1], p[1],
                       fmaf(w[2], p[2], fmaf(w[3], p[3], s[k]))));
            }
        }
        #pragma unroll
        for (int k = 0; k < 8; ++k) {
            float v = s[k];
            #pragma unroll
            for (int m = 1; m < 64; m <<= 1) v += __shfl_xor(v, m, 64);
            if (lane == 0) outT[(h0 + k) * 64 + bt] = v + b2[h0 + k];
        }
    }
    if (tid == 0) outT[512 * 64 + bt] = 1.0f;
}

// ---------------------------------------------------------------------------
// Kernel 2: bilinear h[bt,o] = relu( a^T W_o b + fb1[o] ).
// Grid 1024 x 512 thr; one block per o.
// WAVE-AUTONOMOUS: wave w owns e in [64w, 64w+64) x all 64 bt. Private LDS
// ring (2 x [W 8x64 | a 8x64]) staged by the wave's own global_load_lds,
// paced by its own counted vmcnt(4). NO barriers in the main loop.
// Lane = (bq = lane>>3, eq = lane&7): acc[8e][8bt]; per dd: 4 multicast
// ds_read_b128 + 64 FMA.
// Ring safety: stage(c+2) into buf(c&1) issues after compute(c)'s reads are
// consumed (program order; compiler barrier keeps reads above the DMA).
// Tail: chunks 64/65 clamp to 63 (dup-stage into a dead buffer, in-bounds).
// ---------------------------------------------------------------------------
__global__ __launch_bounds__(512, 2) void bilinear_kernel(
    const float* __restrict__ fw1,  // (1024, 263169)
    const float* __restrict__ fb1,  // (1024)
    const float* __restrict__ aT,   // (513, 64)
    const float* __restrict__ bT,   // (513, 64)
    float* __restrict__ hbuf)       // (64, 1024)
{
    __shared__ float ring[8][2][1024];  // 64 KB: [wave][buf][ W 512 | a 512 ]
    __shared__ float red[16][64];       // 4 KB: [w]=main, [8+w]=e512 partial

    const int tid = threadIdx.x;
    const int lane = tid & 63, w = tid >> 6;
    const int o = blockIdx.x;
    const float* __restrict__ W = fw1 + (size_t)o * TD;

    const int eq = lane & 7;            // e-octet within wave
    const int bq = lane >> 3;           // bt-octet
    const int ebase = w * 64 + eq * 8;  // first of this lane's 8 e
    const int btbase = bq * 8;          // first of this lane's 8 bt

    // DMA lane-mapping (width 16): dest linear float idx = lane*4
    const int srow = lane >> 4;         // row-in-group 0..3
    const int scol = (lane & 15) * 4;   // col float offset
    float* const myring = &ring[w][0][0];

    #define STAGE(buf_, c_)                                                    \
        do {                                                                   \
            float* dst_ = myring + (buf_) * 1024 + lane * 4;                   \
            const float* ws_ = W + (size_t)((c_) * 8 + srow) * AB + (w * 64 + scol); \
            const float* as_ = aT + (size_t)((c_) * 8 + srow) * 64 + scol;     \
            __builtin_amdgcn_global_load_lds((const GAS uint32_t*)(const void*)ws_, \
                (LAS uint32_t*)(void*)dst_, 16, 0, 0);                         \
            __builtin_amdgcn_global_load_lds((const GAS uint32_t*)(const void*)(ws_ + (size_t)4 * AB), \
                (LAS uint32_t*)(void*)(dst_ + 256), 16, 0, 0);                 \
            __builtin_amdgcn_global_load_lds((const GAS uint32_t*)(const void*)as_, \
                (LAS uint32_t*)(void*)(dst_ + 512), 16, 0, 0);                 \
            __builtin_amdgcn_global_load_lds((const GAS uint32_t*)(const void*)(as_ + 4 * 64), \
                (LAS uint32_t*)(void*)(dst_ + 768), 16, 0, 0);                 \
        } while (0)

    float acc[8][8];  // [e-sub][bt-sub]
    #pragma unroll
    for (int i = 0; i < 8; ++i)
        #pragma unroll
        for (int j = 0; j < 8; ++j) acc[i][j] = 0.f;

    STAGE(0, 0);
    STAGE(1, 1);

    #pragma unroll 2
    for (int c = 0; c < 64; ++c) {
        asm volatile("s_waitcnt vmcnt(4)" ::: "memory");  // chunk c landed

        const float* __restrict__ wr = myring + (c & 1) * 1024;
        const float* __restrict__ ar = wr + 512;
        #pragma unroll
        for (int dd = 0; dd < 8; ++dd) {
            const f4 we0 = *(const f4*)&wr[dd * 64 + eq * 8];
            const f4 we1 = *(const f4*)&wr[dd * 64 + eq * 8 + 4];
            const f4 aa0 = *(const f4*)&ar[dd * 64 + btbase];
            const f4 aa1 = *(const f4*)&ar[dd * 64 + btbase + 4];
            #pragma unroll
            for (int j = 0; j < 4; ++j) {
                #pragma unroll
                for (int i = 0; i < 4; ++i) {
                    acc[i][j]         = fmaf(we0[i], aa0[j], acc[i][j]);
                    acc[i + 4][j]     = fmaf(we1[i], aa0[j], acc[i + 4][j]);
                    acc[i][j + 4]     = fmaf(we0[i], aa1[j], acc[i][j + 4]);
                    acc[i + 4][j + 4] = fmaf(we1[i], aa1[j], acc[i + 4][j + 4]);
                }
            }
        }
        asm volatile("" ::: "memory");  // reads stay above the refill DMA
        const int nc = (c < 62) ? (c + 2) : 63;
        STAGE(c & 1, nc);
    }

    // d = 512 row (a == 1): acc[i][j] += W[512, ebase+i]
    {
        const f4 r0 = *(const f4*)(W + (size_t)512 * AB + ebase);
        const f4 r1 = *(const f4*)(W + (size_t)512 * AB + ebase + 4);
        #pragma unroll
        for (int j = 0; j < 8; ++j)
            #pragma unroll
            for (int i = 0; i < 4; ++i) {
                acc[i][j] += r0[i];
                acc[i + 4][j] += r1[i];
            }
    }

    // b-scale: y[j] = sum_i acc[i][j] * b[ebase+i, btbase+j]
    float y[8];
    #pragma unroll
    for (int j = 0; j < 8; ++j) y[j] = 0.f;
    #pragma unroll
    for (int i = 0; i < 8; ++i) {
        const float* br = bT + (size_t)(ebase + i) * 64 + btbase;
        const f4 b0 = *(const f4*)br;
        const f4 b1 = *(const f4*)(br + 4);
        #pragma unroll
        for (int j = 0; j < 4; ++j) {
            y[j]     = fmaf(acc[i][j],     b0[j], y[j]);
            y[j + 4] = fmaf(acc[i][j + 4], b1[j], y[j + 4]);
        }
    }

    // reduce over the 8 eq-groups (lane bits 0..2)
    #pragma unroll
    for (int j = 0; j < 8; ++j) {
        float v = y[j];
        v += __shfl_xor(v, 1, 64);
        v += __shfl_xor(v, 2, 64);
        v += __shfl_xor(v, 4, 64);
        y[j] = v;
    }
    if (eq == 0) {
        f4 y0 = {y[0], y[1], y[2], y[3]};
        f4 y1 = {y[4], y[5], y[6], y[7]};
        *(f4*)&red[w][btbase] = y0;
        *(f4*)&red[w][btbase + 4] = y1;
    }

    // e = 512 column (b == 1), this wave's d-range, lane = bt
    {
        const int d0 = w * 64;
        float s0 = 0.f, s1 = 0.f, s2 = 0.f, s3 = 0.f;
        #pragma unroll 4
        for (int k = 0; k < 64; k += 4) {
            s0 = fmaf(aT[(size_t)(d0 + k) * 64 + lane],
                      W[(size_t)(d0 + k) * AB + 512], s0);
            s1 = fmaf(aT[(size_t)(d0 + k + 1) * 64 + lane],
                      W[(size_t)(d0 + k + 1) * AB + 512], s1);
            s2 = fmaf(aT[(size_t)(d0 + k + 2) * 64 + lane],
                      W[(size_t)(d0 + k + 2) * AB + 512], s2);
            s3 = fmaf(aT[(size_t)(d0 + k + 3) * 64 + lane],
                      W[(size_t)(d0 + k + 3) * AB + 512], s3);
        }
        red[8 + w][lane] = (s0 + s1) + (s2 + s3);
    }

    __syncthreads();

    // final fold: wave 0, lane = bt
    if (w == 0) {
        float t = 0.f;
        #pragma unroll
        for (int k = 0; k < 16; ++k) t += red[k][lane];
        t += W[(size_t)512 * AB + 512];  // corner d=512,e=512 (a=b=1)
        t += fb1[o];
        hbuf[(size_t)lane * 1024 + o] = fmaxf(t, 0.f);
    }
    #undef STAGE
}

// ---------------------------------------------------------------------------
// Kernel 3a: fused[bt, f] = h[bt, :] @ fw2[f, :] + fb2[f]
// ---------------------------------------------------------------------------
__global__ __launch_bounds__(256) void fuse2_kernel(
    const float* __restrict__ hbuf,  // (64, 1024)
    const float* __restrict__ fw2,   // (512, 1024)
    const float* __restrict__ fb2,   // (512)
    float* __restrict__ fused)       // (64, 512)
{
    __shared__ float h_sh[1024];
    const int bt = blockIdx.x, tid = threadIdx.x;
    const int lane = tid & 63, wid = tid >> 6;
    *(f4*)&h_sh[tid * 4] = *(const f4*)&hbuf[bt * 1024 + tid * 4];
    __syncthreads();
    for (int f0 = wid * 8; f0 < 512; f0 += 32) {
        float s[8];
        #pragma unroll
        for (int k = 0; k < 8; ++k) s[k] = 0.f;
        #pragma unroll
        for (int it = 0; it < 4; ++it) {
            const int d = it * 256 + lane * 4;
            const f4 p = *(const f4*)&h_sh[d];
            #pragma unroll
            for (int k = 0; k < 8; ++k) {
                const f4 w = *(const f4*)&fw2[(size_t)(f0 + k) * 1024 + d];
                s[k] = fmaf(w[0], p[0], fmaf(w[1], p[1],
                       fmaf(w[2], p[2], fmaf(w[3], p[3], s[k]))));
            }
        }
        #pragma unroll
        for (int k = 0; k < 8; ++k) {
            float v = s[k];
            #pragma unroll
            for (int m = 1; m < 64; m <<= 1) v += __shfl_xor(v, m, 64);
            if (lane == 0) fused[bt * 512 + f0 + k] = v + fb2[f0 + k];
        }
    }
}

// ---------------------------------------------------------------------------
// Kernel 3b: LIF over time. 1024 independent (b, d) chains, T = 32.
// ---------------------------------------------------------------------------
__global__ __launch_bounds__(256) void lif_kernel(
    const float* __restrict__ fused,  // (2, 32, 512)
    float* __restrict__ out)          // (2, 32, 512)
{
    const int idx = blockIdx.x * 256 + threadIdx.x;
    if (idx >= 1024) return;
    const int b = idx >> 9, dd = idx & 511;
    float mem = 0.f;
    for (int t = 0; t < 32; ++t) {
        const size_t off = ((size_t)(b * 32 + t) * 512) + dd;
        mem = 0.9f * mem + fused[off];
        const float s = (mem >= 1.0f) ? 1.0f : 0.0f;
        out[off] = s;
        mem -= s;
    }
}

// ---------------------------------------------------------------------------
extern "C" void kernel_launch(void* const* d_in, const int* in_sizes, int n_in,
                              void* d_out, int out_size, void* d_ws, size_t ws_size,
                              hipStream_t stream) {
    const float* vision = (const float*)d_in[0];
    const float* audio  = (const float*)d_in[1];
    const float* vw1 = (const float*)d_in[2];
    const float* vb1 = (const float*)d_in[3];
    const float* vw2 = (const float*)d_in[4];
    const float* vb2 = (const float*)d_in[5];
    const float* aw1 = (const float*)d_in[6];
    const float* ab1 = (const float*)d_in[7];
    const float* aw2 = (const float*)d_in[8];
    const float* ab2 = (const float*)d_in[9];
    const float* fw1 = (const float*)d_in[10];
    const float* fb1 = (const float*)d_in[11];
    const float* fw2 = (const float*)d_in[12];
    const float* fb2 = (const float*)d_in[13];
    float* out = (float*)d_out;

    float* ws    = (float*)d_ws;
    float* aT    = ws;                 // 513*64
    float* bT    = aT + AB * 64;       // 513*64
    float* hbuf  = bT + AB * 64;       // 64*1024
    float* fused = hbuf + 64 * 1024;   // 64*512

    unimodal_kernel<<<128, 256, 0, stream>>>(vision, audio,
        vw1, vb1, vw2, vb2, aw1, ab1, aw2, ab2, aT, bT);
    bilinear_kernel<<<1024, 512, 0, stream>>>(fw1, fb1, aT, bT, hbuf);
    fuse2_kernel<<<64, 256, 0, stream>>>(hbuf, fw2, fb2, fused);
    lif_kernel<<<4, 256, 0, stream>>>(fused, out);
}

// Round 9
// 577.371 us; speedup vs baseline: 1.1741x; 1.0085x over previous
//
#include <hip/hip_runtime.h>

#define AB 513
#define TD 263169  // 513*513

typedef float f4 __attribute__((ext_vector_type(4)));
#define GAS __attribute__((address_space(1)))
#define LAS __attribute__((address_space(3)))

// ---------------------------------------------------------------------------
// Kernel 1a: pool over S. Blocks 0..63 = vision bt, 64..127 = audio bt.
// Writes TRANSPOSED pT[d][bt] (scattered 4B stores; only 327 KB total).
// ---------------------------------------------------------------------------
__global__ __launch_bounds__(256) void pool_kernel(
    const float* __restrict__ vx, const float* __restrict__ ax,
    float* __restrict__ pvT, float* __restrict__ paT)
{
    const int isA = (blockIdx.x >= 64);
    const int bt = blockIdx.x & 63;
    const float* x = isA ? ax : vx;
    float* pT = isA ? paT : pvT;
    const int D = isA ? 512 : 768;
    const int nd4 = D >> 2;
    const int tid = threadIdx.x;
    if (tid < nd4) {
        f4 s0 = {0.f, 0.f, 0.f, 0.f}, s1 = s0, s2 = s0, s3 = s0;
        const float* xp = x + (size_t)bt * 64 * D + tid * 4;
        #pragma unroll 4
        for (int ss = 0; ss < 64; ss += 4) {
            s0 += *(const f4*)(xp + (size_t)ss * D);
            s1 += *(const f4*)(xp + (size_t)(ss + 1) * D);
            s2 += *(const f4*)(xp + (size_t)(ss + 2) * D);
            s3 += *(const f4*)(xp + (size_t)(ss + 3) * D);
        }
        const f4 s = ((s0 + s1) + (s2 + s3)) * 0.015625f;
        #pragma unroll
        for (int q = 0; q < 4; ++q) pT[(tid * 4 + q) * 64 + bt] = s[q];
    }
}

// ---------------------------------------------------------------------------
// Kernel 1b: layer1, weight-stationary. Block = 8-h tile (64 v + 64 a blocks);
// wave = one h row; lane = bt. Weights read once total; pT coalesced.
// ---------------------------------------------------------------------------
__global__ __launch_bounds__(512) void mlp1_kernel(
    const float* __restrict__ pvT, const float* __restrict__ paT,
    const float* __restrict__ vw1, const float* __restrict__ vb1,
    const float* __restrict__ aw1, const float* __restrict__ ab1,
    float* __restrict__ h1vT, float* __restrict__ h1aT)
{
    const int isA = (blockIdx.x >= 64);
    const int D = isA ? 512 : 768;
    const float* pT = isA ? paT : pvT;
    const float* w1 = isA ? aw1 : vw1;
    const float* b1 = isA ? ab1 : vb1;
    float* h1T = isA ? h1aT : h1vT;
    const int tid = threadIdx.x, lane = tid & 63, w = tid >> 6;
    const int h = (blockIdx.x & 63) * 8 + w;
    const float* wr = w1 + (size_t)h * D;

    float a0 = 0.f, a1 = 0.f, a2 = 0.f, a3 = 0.f;
    for (int d = 0; d < D; d += 16) {
        const f4 w0 = *(const f4*)(wr + d);
        const f4 w1v = *(const f4*)(wr + d + 4);
        const f4 w2v = *(const f4*)(wr + d + 8);
        const f4 w3v = *(const f4*)(wr + d + 12);
        #pragma unroll
        for (int q = 0; q < 4; ++q) {
            a0 = fmaf(w0[q],  pT[(d + q) * 64 + lane], a0);
            a1 = fmaf(w1v[q], pT[(d + 4 + q) * 64 + lane], a1);
            a2 = fmaf(w2v[q], pT[(d + 8 + q) * 64 + lane], a2);
            a3 = fmaf(w3v[q], pT[(d + 12 + q) * 64 + lane], a3);
        }
    }
    h1T[h * 64 + lane] = fmaxf((a0 + a1) + (a2 + a3) + b1[h], 0.f);
}

// ---------------------------------------------------------------------------
// Kernel 1c: layer2 (no relu) + trailing ones row. Same structure, D = 512.
// Writes aT/bT in the (513, 64) transposed layout bilinear consumes.
// ---------------------------------------------------------------------------
__global__ __launch_bounds__(512) void mlp2_kernel(
    const float* __restrict__ h1vT, const float* __restrict__ h1aT,
    const float* __restrict__ vw2, const float* __restrict__ vb2,
    const float* __restrict__ aw2, const float* __restrict__ ab2,
    float* __restrict__ aTout, float* __restrict__ bTout)
{
    const int isA = (blockIdx.x >= 64);
    const float* hT = isA ? h1aT : h1vT;
    const float* w2 = isA ? aw2 : vw2;
    const float* b2 = isA ? ab2 : vb2;
    float* outT = isA ? bTout : aTout;
    const int tid = threadIdx.x, lane = tid & 63, w = tid >> 6;
    const int h = (blockIdx.x & 63) * 8 + w;
    const float* wr = w2 + (size_t)h * 512;

    float a0 = 0.f, a1 = 0.f, a2 = 0.f, a3 = 0.f;
    for (int d = 0; d < 512; d += 16) {
        const f4 w0 = *(const f4*)(wr + d);
        const f4 w1v = *(const f4*)(wr + d + 4);
        const f4 w2v = *(const f4*)(wr + d + 8);
        const f4 w3v = *(const f4*)(wr + d + 12);
        #pragma unroll
        for (int q = 0; q < 4; ++q) {
            a0 = fmaf(w0[q],  hT[(d + q) * 64 + lane], a0);
            a1 = fmaf(w1v[q], hT[(d + 4 + q) * 64 + lane], a1);
            a2 = fmaf(w2v[q], hT[(d + 8 + q) * 64 + lane], a2);
            a3 = fmaf(w3v[q], hT[(d + 12 + q) * 64 + lane], a3);
        }
    }
    outT[h * 64 + lane] = (a0 + a1) + (a2 + a3) + b2[h];
    if ((blockIdx.x & 63) == 0 && tid < 64) outT[512 * 64 + tid] = 1.0f;
}

// ---------------------------------------------------------------------------
// Kernel 2: bilinear h[bt,o] = relu( a^T W_o b + fb1[o] ).
// Wave-autonomous (R8 structure) + per-wave chunk-sequence ROTATION by w*8:
// waves touch disjoint W regions at any instant -> decorrelated stalls.
// Output now stored transposed: hbufT[o][bt] (contiguous lane store).
// ---------------------------------------------------------------------------
__global__ __launch_bounds__(512, 2) void bilinear_kernel(
    const float* __restrict__ fw1,  // (1024, 263169)
    const float* __restrict__ fb1,  // (1024)
    const float* __restrict__ aT,   // (513, 64)
    const float* __restrict__ bT,   // (513, 64)
    float* __restrict__ hbufT)      // (1024, 64)
{
    __shared__ float ring[8][2][1024];  // 64 KB: [wave][buf][ W 512 | a 512 ]
    __shared__ float red[16][64];       // [w]=main partial, [8+w]=e512 partial

    const int tid = threadIdx.x;
    const int lane = tid & 63, w = tid >> 6;
    const int o = blockIdx.x;
    const float* __restrict__ W = fw1 + (size_t)o * TD;

    const int eq = lane & 7;
    const int bq = lane >> 3;
    const int ebase = w * 64 + eq * 8;
    const int btbase = bq * 8;

    const int srow = lane >> 4;
    const int scol = (lane & 15) * 4;
    float* const myring = &ring[w][0][0];

    #define STAGE(buf_, c_)                                                    \
        do {                                                                   \
            float* dst_ = myring + (buf_) * 1024 + lane * 4;                   \
            const float* ws_ = W + (size_t)((c_) * 8 + srow) * AB + (w * 64 + scol); \
            const float* as_ = aT + (size_t)((c_) * 8 + srow) * 64 + scol;     \
            __builtin_amdgcn_global_load_lds((const GAS uint32_t*)(const void*)ws_, \
                (LAS uint32_t*)(void*)dst_, 16, 0, 0);                         \
            __builtin_amdgcn_global_load_lds((const GAS uint32_t*)(const void*)(ws_ + (size_t)4 * AB), \
                (LAS uint32_t*)(void*)(dst_ + 256), 16, 0, 0);                 \
            __builtin_amdgcn_global_load_lds((const GAS uint32_t*)(const void*)as_, \
                (LAS uint32_t*)(void*)(dst_ + 512), 16, 0, 0);                 \
            __builtin_amdgcn_global_load_lds((const GAS uint32_t*)(const void*)(as_ + 4 * 64), \
                (LAS uint32_t*)(void*)(dst_ + 768), 16, 0, 0);                 \
        } while (0)

    float acc[8][8];  // [e-sub][bt-sub]
    #pragma unroll
    for (int i = 0; i < 8; ++i)
        #pragma unroll
        for (int j = 0; j < 8; ++j) acc[i][j] = 0.f;

    const int rot = w * 8;
    STAGE(0, rot);
    STAGE(1, (rot + 1) & 63);

    #pragma unroll 2
    for (int c = 0; c < 64; ++c) {
        asm volatile("s_waitcnt vmcnt(4)" ::: "memory");  // chunk c landed

        const float* __restrict__ wr = myring + (c & 1) * 1024;
        const float* __restrict__ ar = wr + 512;
        #pragma unroll
        for (int dd = 0; dd < 8; ++dd) {
            const f4 we0 = *(const f4*)&wr[dd * 64 + eq * 8];
            const f4 we1 = *(const f4*)&wr[dd * 64 + eq * 8 + 4];
            const f4 aa0 = *(const f4*)&ar[dd * 64 + btbase];
            const f4 aa1 = *(const f4*)&ar[dd * 64 + btbase + 4];
            #pragma unroll
            for (int j = 0; j < 4; ++j) {
                #pragma unroll
                for (int i = 0; i < 4; ++i) {
                    acc[i][j]         = fmaf(we0[i], aa0[j], acc[i][j]);
                    acc[i + 4][j]     = fmaf(we1[i], aa0[j], acc[i + 4][j]);
                    acc[i][j + 4]     = fmaf(we0[i], aa1[j], acc[i][j + 4]);
                    acc[i + 4][j + 4] = fmaf(we1[i], aa1[j], acc[i + 4][j + 4]);
                }
            }
        }
        asm volatile("" ::: "memory");  // reads stay above the refill DMA
        STAGE(c & 1, (c + 2 + rot) & 63);  // wraps at 62/63: dead buffer, safe
    }

    // d = 512 row (a == 1): acc[i][j] += W[512, ebase+i]
    {
        const f4 r0 = *(const f4*)(W + (size_t)512 * AB + ebase);
        const f4 r1 = *(const f4*)(W + (size_t)512 * AB + ebase + 4);
        #pragma unroll
        for (int j = 0; j < 8; ++j)
            #pragma unroll
            for (int i = 0; i < 4; ++i) {
                acc[i][j] += r0[i];
                acc[i + 4][j] += r1[i];
            }
    }

    // b-scale: y[j] = sum_i acc[i][j] * b[ebase+i, btbase+j]
    float y[8];
    #pragma unroll
    for (int j = 0; j < 8; ++j) y[j] = 0.f;
    #pragma unroll
    for (int i = 0; i < 8; ++i) {
        const float* br = bT + (size_t)(ebase + i) * 64 + btbase;
        const f4 b0 = *(const f4*)br;
        const f4 b1 = *(const f4*)(br + 4);
        #pragma unroll
        for (int j = 0; j < 4; ++j) {
            y[j]     = fmaf(acc[i][j],     b0[j], y[j]);
            y[j + 4] = fmaf(acc[i][j + 4], b1[j], y[j + 4]);
        }
    }

    // reduce over the 8 eq-groups (lane bits 0..2)
    #pragma unroll
    for (int j = 0; j < 8; ++j) {
        float v = y[j];
        v += __shfl_xor(v, 1, 64);
        v += __shfl_xor(v, 2, 64);
        v += __shfl_xor(v, 4, 64);
        y[j] = v;
    }
    if (eq == 0) {
        f4 y0 = {y[0], y[1], y[2], y[3]};
        f4 y1 = {y[4], y[5], y[6], y[7]};
        *(f4*)&red[w][btbase] = y0;
        *(f4*)&red[w][btbase + 4] = y1;
    }

    // e = 512 column (b == 1), this wave's d-range, lane = bt
    {
        const int d0 = w * 64;
        float s0 = 0.f, s1 = 0.f, s2 = 0.f, s3 = 0.f;
        #pragma unroll 4
        for (int k = 0; k < 64; k += 4) {
            s0 = fmaf(aT[(size_t)(d0 + k) * 64 + lane],
                      W[(size_t)(d0 + k) * AB + 512], s0);
            s1 = fmaf(aT[(size_t)(d0 + k + 1) * 64 + lane],
                      W[(size_t)(d0 + k + 1) * AB + 512], s1);
            s2 = fmaf(aT[(size_t)(d0 + k + 2) * 64 + lane],
                      W[(size_t)(d0 + k + 2) * AB + 512], s2);
            s3 = fmaf(aT[(size_t)(d0 + k + 3) * 64 + lane],
                      W[(size_t)(d0 + k + 3) * AB + 512], s3);
        }
        red[8 + w][lane] = (s0 + s1) + (s2 + s3);
    }

    __syncthreads();

    // final fold: wave 0, lane = bt; contiguous store to hbufT[o][bt]
    if (w == 0) {
        float t = 0.f;
        #pragma unroll
        for (int k = 0; k < 16; ++k) t += red[k][lane];
        t += W[(size_t)512 * AB + 512];  // corner d=512,e=512 (a=b=1)
        t += fb1[o];
        hbufT[(size_t)o * 64 + lane] = fmaxf(t, 0.f);
    }
    #undef STAGE
}

// ---------------------------------------------------------------------------
// Kernel 3a: fused[bt, f] = h[bt, :] @ fw2[f, :] + fb2[f].
// Weight-stationary: block = 16-f tile (32 blocks), wave = 2 f, lane = bt.
// ---------------------------------------------------------------------------
__global__ __launch_bounds__(512) void fuse2_kernel(
    const float* __restrict__ hbufT,  // (1024, 64)
    const float* __restrict__ fw2,    // (512, 1024)
    const float* __restrict__ fb2,    // (512)
    float* __restrict__ fused)        // (64, 512)
{
    const int tid = threadIdx.x, lane = tid & 63, w = tid >> 6;
    #pragma unroll
    for (int k = 0; k < 2; ++k) {
        const int f = blockIdx.x * 16 + w * 2 + k;
        const float* wr = fw2 + (size_t)f * 1024;
        float a0 = 0.f, a1 = 0.f, a2 = 0.f, a3 = 0.f;
        for (int o = 0; o < 1024; o += 16) {
            const f4 w0 = *(const f4*)(wr + o);
            const f4 w1v = *(const f4*)(wr + o + 4);
            const f4 w2v = *(const f4*)(wr + o + 8);
            const f4 w3v = *(const f4*)(wr + o + 12);
            #pragma unroll
            for (int q = 0; q < 4; ++q) {
                a0 = fmaf(w0[q],  hbufT[(o + q) * 64 + lane], a0);
                a1 = fmaf(w1v[q], hbufT[(o + 4 + q) * 64 + lane], a1);
                a2 = fmaf(w2v[q], hbufT[(o + 8 + q) * 64 + lane], a2);
                a3 = fmaf(w3v[q], hbufT[(o + 12 + q) * 64 + lane], a3);
            }
        }
        fused[lane * 512 + f] = (a0 + a1) + (a2 + a3) + fb2[f];
    }
}

// ---------------------------------------------------------------------------
// Kernel 3b: LIF over time. 1024 independent (b, d) chains, T = 32.
// ---------------------------------------------------------------------------
__global__ __launch_bounds__(256) void lif_kernel(
    const float* __restrict__ fused,  // (2, 32, 512)
    float* __restrict__ out)          // (2, 32, 512)
{
    const int idx = blockIdx.x * 256 + threadIdx.x;
    if (idx >= 1024) return;
    const int b = idx >> 9, dd = idx & 511;
    float mem = 0.f;
    for (int t = 0; t < 32; ++t) {
        const size_t off = ((size_t)(b * 32 + t) * 512) + dd;
        mem = 0.9f * mem + fused[off];
        const float s = (mem >= 1.0f) ? 1.0f : 0.0f;
        out[off] = s;
        mem -= s;
    }
}

// ---------------------------------------------------------------------------
extern "C" void kernel_launch(void* const* d_in, const int* in_sizes, int n_in,
                              void* d_out, int out_size, void* d_ws, size_t ws_size,
                              hipStream_t stream) {
    const float* vision = (const float*)d_in[0];
    const float* audio  = (const float*)d_in[1];
    const float* vw1 = (const float*)d_in[2];
    const float* vb1 = (const float*)d_in[3];
    const float* vw2 = (const float*)d_in[4];
    const float* vb2 = (const float*)d_in[5];
    const float* aw1 = (const float*)d_in[6];
    const float* ab1 = (const float*)d_in[7];
    const float* aw2 = (const float*)d_in[8];
    const float* ab2 = (const float*)d_in[9];
    const float* fw1 = (const float*)d_in[10];
    const float* fb1 = (const float*)d_in[11];
    const float* fw2 = (const float*)d_in[12];
    const float* fb2 = (const float*)d_in[13];
    float* out = (float*)d_out;

    float* ws    = (float*)d_ws;
    float* pvT   = ws;                  // 768*64
    float* paT   = pvT + 768 * 64;      // 512*64
    float* h1vT  = paT + 512 * 64;      // 512*64
    float* h1aT  = h1vT + 512 * 64;     // 512*64
    float* aT    = h1aT + 512 * 64;     // 513*64
    float* bT    = aT + AB * 64;        // 513*64
    float* hbufT = bT + AB * 64;        // 1024*64
    float* fused = hbufT + 1024 * 64;   // 64*512

    pool_kernel<<<128, 256, 0, stream>>>(vision, audio, pvT, paT);
    mlp1_kernel<<<128, 512, 0, stream>>>(pvT, paT, vw1, vb1, aw1, ab1, h1vT, h1aT);
    mlp2_kernel<<<128, 512, 0, stream>>>(h1vT, h1aT, vw2, vb2, aw2, ab2, aT, bT);
    bilinear_kernel<<<1024, 512, 0, stream>>>(fw1, fb1, aT, bT, hbufT);
    fuse2_kernel<<<32, 512, 0, stream>>>(hbufT, fw2, fb2, fused);
    lif_kernel<<<4, 256, 0, stream>>>(fused, out);
}

// Round 10
// 437.431 us; speedup vs baseline: 1.5497x; 1.3199x over previous
//
#include <hip/hip_runtime.h>

#define AB 513
#define TD 263169  // 513*513

typedef float f4 __attribute__((ext_vector_type(4)));
typedef float f32x4 __attribute__((ext_vector_type(4)));
typedef short bf16x8 __attribute__((ext_vector_type(8)));
typedef int i32x4 __attribute__((ext_vector_type(4)));
#define GAS __attribute__((address_space(1)))
#define LAS __attribute__((address_space(3)))

// ---------------------------------------------------------------------------
// Kernel 1a: pool over S. Blocks 0..63 = vision bt, 64..127 = audio bt.
// ---------------------------------------------------------------------------
__global__ __launch_bounds__(256) void pool_kernel(
    const float* __restrict__ vx, const float* __restrict__ ax,
    float* __restrict__ pvT, float* __restrict__ paT)
{
    const int isA = (blockIdx.x >= 64);
    const int bt = blockIdx.x & 63;
    const float* x = isA ? ax : vx;
    float* pT = isA ? paT : pvT;
    const int D = isA ? 512 : 768;
    const int nd4 = D >> 2;
    const int tid = threadIdx.x;
    if (tid < nd4) {
        f4 s0 = {0.f, 0.f, 0.f, 0.f}, s1 = s0, s2 = s0, s3 = s0;
        const float* xp = x + (size_t)bt * 64 * D + tid * 4;
        #pragma unroll 4
        for (int ss = 0; ss < 64; ss += 4) {
            s0 += *(const f4*)(xp + (size_t)ss * D);
            s1 += *(const f4*)(xp + (size_t)(ss + 1) * D);
            s2 += *(const f4*)(xp + (size_t)(ss + 2) * D);
            s3 += *(const f4*)(xp + (size_t)(ss + 3) * D);
        }
        const f4 s = ((s0 + s1) + (s2 + s3)) * 0.015625f;
        #pragma unroll
        for (int q = 0; q < 4; ++q) pT[(tid * 4 + q) * 64 + bt] = s[q];
    }
}

// ---------------------------------------------------------------------------
// Kernel 1b: layer1, weight-stationary. Block = 8-h tile; wave = h row.
// ---------------------------------------------------------------------------
__global__ __launch_bounds__(512) void mlp1_kernel(
    const float* __restrict__ pvT, const float* __restrict__ paT,
    const float* __restrict__ vw1, const float* __restrict__ vb1,
    const float* __restrict__ aw1, const float* __restrict__ ab1,
    float* __restrict__ h1vT, float* __restrict__ h1aT)
{
    const int isA = (blockIdx.x >= 64);
    const int D = isA ? 512 : 768;
    const float* pT = isA ? paT : pvT;
    const float* w1 = isA ? aw1 : vw1;
    const float* b1 = isA ? ab1 : vb1;
    float* h1T = isA ? h1aT : h1vT;
    const int tid = threadIdx.x, lane = tid & 63, w = tid >> 6;
    const int h = (blockIdx.x & 63) * 8 + w;
    const float* wr = w1 + (size_t)h * D;

    float a0 = 0.f, a1 = 0.f, a2 = 0.f, a3 = 0.f;
    for (int d = 0; d < D; d += 16) {
        const f4 w0 = *(const f4*)(wr + d);
        const f4 w1v = *(const f4*)(wr + d + 4);
        const f4 w2v = *(const f4*)(wr + d + 8);
        const f4 w3v = *(const f4*)(wr + d + 12);
        #pragma unroll
        for (int q = 0; q < 4; ++q) {
            a0 = fmaf(w0[q],  pT[(d + q) * 64 + lane], a0);
            a1 = fmaf(w1v[q], pT[(d + 4 + q) * 64 + lane], a1);
            a2 = fmaf(w2v[q], pT[(d + 8 + q) * 64 + lane], a2);
            a3 = fmaf(w3v[q], pT[(d + 12 + q) * 64 + lane], a3);
        }
    }
    h1T[h * 64 + lane] = fmaxf((a0 + a1) + (a2 + a3) + b1[h], 0.f);
}

// ---------------------------------------------------------------------------
// Kernel 1c: layer2 (no relu) + trailing ones row.
// ---------------------------------------------------------------------------
__global__ __launch_bounds__(512) void mlp2_kernel(
    const float* __restrict__ h1vT, const float* __restrict__ h1aT,
    const float* __restrict__ vw2, const float* __restrict__ vb2,
    const float* __restrict__ aw2, const float* __restrict__ ab2,
    float* __restrict__ aTout, float* __restrict__ bTout)
{
    const int isA = (blockIdx.x >= 64);
    const float* hT = isA ? h1aT : h1vT;
    const float* w2 = isA ? aw2 : vw2;
    const float* b2 = isA ? ab2 : vb2;
    float* outT = isA ? bTout : aTout;
    const int tid = threadIdx.x, lane = tid & 63, w = tid >> 6;
    const int h = (blockIdx.x & 63) * 8 + w;
    const float* wr = w2 + (size_t)h * 512;

    float a0 = 0.f, a1 = 0.f, a2 = 0.f, a3 = 0.f;
    for (int d = 0; d < 512; d += 16) {
        const f4 w0 = *(const f4*)(wr + d);
        const f4 w1v = *(const f4*)(wr + d + 4);
        const f4 w2v = *(const f4*)(wr + d + 8);
        const f4 w3v = *(const f4*)(wr + d + 12);
        #pragma unroll
        for (int q = 0; q < 4; ++q) {
            a0 = fmaf(w0[q],  hT[(d + q) * 64 + lane], a0);
            a1 = fmaf(w1v[q], hT[(d + 4 + q) * 64 + lane], a1);
            a2 = fmaf(w2v[q], hT[(d + 8 + q) * 64 + lane], a2);
            a3 = fmaf(w3v[q], hT[(d + 12 + q) * 64 + lane], a3);
        }
    }
    outT[h * 64 + lane] = (a0 + a1) + (a2 + a3) + b2[h];
    if ((blockIdx.x & 63) == 0 && tid < 64) outT[512 * 64 + tid] = 1.0f;
}

// ---------------------------------------------------------------------------
// Kernel 1d: split aT into 3 truncated-bf16 levels, packed in MFMA A-fragment
// order: aF[((kt*4+mt)*64+lane)*8 + i] = lvl(A[m][k]), m = mt*16+(lane&15),
// k = kt*32 + (lane>>4)*8 + i.  (o-independent; read by all bilinear blocks)
// ---------------------------------------------------------------------------
__global__ __launch_bounds__(256) void aprep_kernel(
    const float* __restrict__ aT,   // (513, 64)
    short* __restrict__ aF1, short* __restrict__ aF2, short* __restrict__ aF3)
{
    const int t = blockIdx.x * 256 + threadIdx.x;  // [0, 4096)
    const int l = t & 63, mt = (t >> 6) & 3, kt = t >> 8;
    const int m = mt * 16 + (l & 15);
    const int kbase = kt * 32 + ((l >> 4) << 3);
    const int obase = ((kt * 4 + mt) * 64 + l) * 8;
    #pragma unroll
    for (int i = 0; i < 8; ++i) {
        const float v = aT[(size_t)(kbase + i) * 64 + m];
        const unsigned u = __float_as_uint(v);
        const float r1 = v - __uint_as_float(u & 0xFFFF0000u);
        const unsigned u1 = __float_as_uint(r1);
        const float r2 = r1 - __uint_as_float(u1 & 0xFFFF0000u);
        const unsigned u2 = __float_as_uint(r2);
        aF1[obase + i] = (short)(u >> 16);
        aF2[obase + i] = (short)(u1 >> 16);
        aF3[obase + i] = (short)(u2 >> 16);
    }
}

// ---------------------------------------------------------------------------
// Kernel 2: bilinear h[bt,o] = relu( a^T W_o b + fb1[o] ) via bf16-split MFMA.
// Grid 1024 x 512; one block per o; 1 block/CU (128 KB LDS ring).
// Wave w owns e in [64w, 64w+64); private 2-deep ring of 32d x 64e chunks
// staged by its own global_load_lds (8 x width-16 per chunk), counted vmcnt.
// Per chunk (= one K-step of 32): 12 A-frag loads (L2), per nt: 8 ds_read_b32
// + 3-level truncated-bf16 split/pack + 4mt x 6 mfma_f32_16x16x32_bf16.
// Split exactness: v = v1+v2+v3+rho, |rho|<=2^-24|v|; products kept down to
// 2^-16 scale -> P error ~1e-8 rel. Epilogue: b-scale (fp32) + shfl reduce;
// d=512 row, e=512 col, corner in exact fp32. red[] aliases drained ring.
// ---------------------------------------------------------------------------
__global__ __launch_bounds__(512, 1) void bilinear_kernel(
    const float* __restrict__ fw1,  // (1024, 263169)
    const float* __restrict__ fb1,  // (1024)
    const float* __restrict__ aT,   // (513, 64)
    const float* __restrict__ bT,   // (513, 64)
    const short* __restrict__ aF1, const short* __restrict__ aF2,
    const short* __restrict__ aF3,
    float* __restrict__ hbufT)      // (1024, 64)
{
    __shared__ float ring[8][2][2048];  // 128 KB
    const int tid = threadIdx.x;
    const int l = tid & 63, w = tid >> 6;
    const int o = blockIdx.x;
    const float* __restrict__ W = fw1 + (size_t)o * TD;
    const int we0 = w * 64;
    const int lq = l >> 4, ln = l & 15;
    float* const myring = &ring[w][0][0];

    #define STAGE(buf_, kt_)                                                   \
        do {                                                                   \
            _Pragma("unroll")                                                  \
            for (int is_ = 0; is_ < 8; ++is_) {                                \
                const int g_ = is_ * 64 + l;                                   \
                const int row_ = g_ >> 4, c4_ = (g_ & 15) * 4;                 \
                __builtin_amdgcn_global_load_lds(                              \
                    (const GAS unsigned*)(const void*)(W + (size_t)((kt_) * 32 + row_) * AB + we0 + c4_), \
                    (LAS unsigned*)(void*)(myring + (buf_) * 2048 + is_ * 256 + l * 4), 16, 0, 0); \
            }                                                                  \
        } while (0)

    f32x4 acc[4][4];
    #pragma unroll
    for (int mt = 0; mt < 4; ++mt)
        #pragma unroll
        for (int nt = 0; nt < 4; ++nt)
            acc[mt][nt] = (f32x4){0.f, 0.f, 0.f, 0.f};

    STAGE(0, 0);
    STAGE(1, 1);

    #pragma unroll 1
    for (int kt = 0; kt < 16; ++kt) {
        if (kt < 15) asm volatile("s_waitcnt vmcnt(8)" ::: "memory");
        else         asm volatile("s_waitcnt vmcnt(0)" ::: "memory");

        // A fragments for this K-step (o-independent, L2-hot)
        bf16x8 A1[4], A2[4], A3[4];
        #pragma unroll
        for (int mt = 0; mt < 4; ++mt) {
            const int fb = ((kt * 4 + mt) * 64 + l) * 8;
            A1[mt] = *(const bf16x8*)(aF1 + fb);
            A2[mt] = *(const bf16x8*)(aF2 + fb);
            A3[mt] = *(const bf16x8*)(aF3 + fb);
        }

        const float* __restrict__ wb = myring + (kt & 1) * 2048;
        #pragma unroll
        for (int nt = 0; nt < 4; ++nt) {
            unsigned u0[8], u1[8], u2[8];
            #pragma unroll
            for (int i = 0; i < 8; ++i) {
                const float v = wb[(lq * 8 + i) * 64 + nt * 16 + ln];
                u0[i] = __float_as_uint(v);
                const float r1 = v - __uint_as_float(u0[i] & 0xFFFF0000u);
                u1[i] = __float_as_uint(r1);
                const float r2 = r1 - __uint_as_float(u1[i] & 0xFFFF0000u);
                u2[i] = __float_as_uint(r2);
            }
            i32x4 p1, p2, p3;
            #pragma unroll
            for (int j = 0; j < 4; ++j) {
                p1[j] = (int)((u0[2 * j + 1] & 0xFFFF0000u) | (u0[2 * j] >> 16));
                p2[j] = (int)((u1[2 * j + 1] & 0xFFFF0000u) | (u1[2 * j] >> 16));
                p3[j] = (int)((u2[2 * j + 1] & 0xFFFF0000u) | (u2[2 * j] >> 16));
            }
            const bf16x8 B1 = __builtin_bit_cast(bf16x8, p1);
            const bf16x8 B2 = __builtin_bit_cast(bf16x8, p2);
            const bf16x8 B3 = __builtin_bit_cast(bf16x8, p3);
            #pragma unroll
            for (int mt = 0; mt < 4; ++mt) {
                acc[mt][nt] = __builtin_amdgcn_mfma_f32_16x16x32_bf16(A1[mt], B1, acc[mt][nt], 0, 0, 0);
                acc[mt][nt] = __builtin_amdgcn_mfma_f32_16x16x32_bf16(A1[mt], B2, acc[mt][nt], 0, 0, 0);
                acc[mt][nt] = __builtin_amdgcn_mfma_f32_16x16x32_bf16(A2[mt], B1, acc[mt][nt], 0, 0, 0);
                acc[mt][nt] = __builtin_amdgcn_mfma_f32_16x16x32_bf16(A2[mt], B2, acc[mt][nt], 0, 0, 0);
                acc[mt][nt] = __builtin_amdgcn_mfma_f32_16x16x32_bf16(A1[mt], B3, acc[mt][nt], 0, 0, 0);
                acc[mt][nt] = __builtin_amdgcn_mfma_f32_16x16x32_bf16(A3[mt], B1, acc[mt][nt], 0, 0, 0);
            }
        }
        asm volatile("" ::: "memory");  // keep refill DMA after the reads
        if (kt + 2 <= 15) STAGE(kt & 1, kt + 2);
    }
    // vmcnt(0) done at kt=15: no DMA in flight -> ring reusable as red[].

    // y[bt] = sum_e P[bt,e] * b[e,bt] over this wave's e-range.
    // P fragment: bt = mt*16 + lq*4 + r, e = we0 + nt*16 + ln.
    float ysum[4][4];
    #pragma unroll
    for (int mt = 0; mt < 4; ++mt)
        #pragma unroll
        for (int r = 0; r < 4; ++r) ysum[mt][r] = 0.f;
    #pragma unroll
    for (int mt = 0; mt < 4; ++mt) {
        const int bt0 = mt * 16 + lq * 4;
        #pragma unroll
        for (int nt = 0; nt < 4; ++nt) {
            const int e = we0 + nt * 16 + ln;
            const f4 bv = *(const f4*)(bT + (size_t)e * 64 + bt0);
            #pragma unroll
            for (int r = 0; r < 4; ++r)
                ysum[mt][r] = fmaf(acc[mt][nt][r], bv[r], ysum[mt][r]);
        }
    }
    #pragma unroll
    for (int mt = 0; mt < 4; ++mt)
        #pragma unroll
        for (int r = 0; r < 4; ++r) {
            float v = ysum[mt][r];
            v += __shfl_xor(v, 1, 64);
            v += __shfl_xor(v, 2, 64);
            v += __shfl_xor(v, 4, 64);
            v += __shfl_xor(v, 8, 64);
            ysum[mt][r] = v;
        }
    if (ln == 0) {
        #pragma unroll
        for (int mt = 0; mt < 4; ++mt)
            #pragma unroll
            for (int r = 0; r < 4; ++r)
                myring[mt * 16 + lq * 4 + r] = ysum[mt][r];  // red_main
    }

    // aux: e=512 col (b==1) over d in wave range + d=512 row (a==1) over
    // e in wave range; lane = bt.
    {
        float s = 0.f;
        #pragma unroll 4
        for (int k = 0; k < 64; ++k)
            s = fmaf(aT[(size_t)(we0 + k) * 64 + l], W[(size_t)(we0 + k) * AB + 512], s);
        #pragma unroll 4
        for (int k = 0; k < 64; ++k)
            s = fmaf(W[(size_t)512 * AB + we0 + k], bT[(size_t)(we0 + k) * 64 + l], s);
        myring[64 + l] = s;  // red_aux
    }

    __syncthreads();

    if (w == 0) {
        float t2 = 0.f;
        #pragma unroll
        for (int k = 0; k < 8; ++k)
            t2 += ring[k][0][l] + ring[k][0][64 + l];
        t2 += W[(size_t)512 * AB + 512] + fb1[o];  // corner (a=b=1)
        hbufT[(size_t)o * 64 + l] = fmaxf(t2, 0.f);
    }
    #undef STAGE
}

// ---------------------------------------------------------------------------
// Kernel 3a: fused[bt, f] = h[bt, :] @ fw2[f, :] + fb2[f].
// ---------------------------------------------------------------------------
__global__ __launch_bounds__(512) void fuse2_kernel(
    const float* __restrict__ hbufT,  // (1024, 64)
    const float* __restrict__ fw2,    // (512, 1024)
    const float* __restrict__ fb2,    // (512)
    float* __restrict__ fused)        // (64, 512)
{
    const int tid = threadIdx.x, lane = tid & 63, w = tid >> 6;
    #pragma unroll
    for (int k = 0; k < 2; ++k) {
        const int f = blockIdx.x * 16 + w * 2 + k;
        const float* wr = fw2 + (size_t)f * 1024;
        float a0 = 0.f, a1 = 0.f, a2 = 0.f, a3 = 0.f;
        for (int o = 0; o < 1024; o += 16) {
            const f4 w0 = *(const f4*)(wr + o);
            const f4 w1v = *(const f4*)(wr + o + 4);
            const f4 w2v = *(const f4*)(wr + o + 8);
            const f4 w3v = *(const f4*)(wr + o + 12);
            #pragma unroll
            for (int q = 0; q < 4; ++q) {
                a0 = fmaf(w0[q],  hbufT[(o + q) * 64 + lane], a0);
                a1 = fmaf(w1v[q], hbufT[(o + 4 + q) * 64 + lane], a1);
                a2 = fmaf(w2v[q], hbufT[(o + 8 + q) * 64 + lane], a2);
                a3 = fmaf(w3v[q], hbufT[(o + 12 + q) * 64 + lane], a3);
            }
        }
        fused[lane * 512 + f] = (a0 + a1) + (a2 + a3) + fb2[f];
    }
}

// ---------------------------------------------------------------------------
// Kernel 3b: LIF over time. 1024 independent (b, d) chains, T = 32.
// ---------------------------------------------------------------------------
__global__ __launch_bounds__(256) void lif_kernel(
    const float* __restrict__ fused,  // (2, 32, 512)
    float* __restrict__ out)          // (2, 32, 512)
{
    const int idx = blockIdx.x * 256 + threadIdx.x;
    if (idx >= 1024) return;
    const int b = idx >> 9, dd = idx & 511;
    float mem = 0.f;
    for (int t = 0; t < 32; ++t) {
        const size_t off = ((size_t)(b * 32 + t) * 512) + dd;
        mem = 0.9f * mem + fused[off];
        const float s = (mem >= 1.0f) ? 1.0f : 0.0f;
        out[off] = s;
        mem -= s;
    }
}

// ---------------------------------------------------------------------------
extern "C" void kernel_launch(void* const* d_in, const int* in_sizes, int n_in,
                              void* d_out, int out_size, void* d_ws, size_t ws_size,
                              hipStream_t stream) {
    const float* vision = (const float*)d_in[0];
    const float* audio  = (const float*)d_in[1];
    const float* vw1 = (const float*)d_in[2];
    const float* vb1 = (const float*)d_in[3];
    const float* vw2 = (const float*)d_in[4];
    const float* vb2 = (const float*)d_in[5];
    const float* aw1 = (const float*)d_in[6];
    const float* ab1 = (const float*)d_in[7];
    const float* aw2 = (const float*)d_in[8];
    const float* ab2 = (const float*)d_in[9];
    const float* fw1 = (const float*)d_in[10];
    const float* fb1 = (const float*)d_in[11];
    const float* fw2 = (const float*)d_in[12];
    const float* fb2 = (const float*)d_in[13];
    float* out = (float*)d_out;

    float* ws    = (float*)d_ws;
    float* pvT   = ws;                  // 768*64
    float* paT   = pvT + 768 * 64;      // 512*64
    float* h1vT  = paT + 512 * 64;      // 512*64
    float* h1aT  = h1vT + 512 * 64;     // 512*64
    float* aT    = h1aT + 512 * 64;     // 513*64
    float* bT    = aT + AB * 64;        // 513*64
    float* hbufT = bT + AB * 64;        // 1024*64
    float* fused = hbufT + 1024 * 64;   // 64*512
    short* aF1   = (short*)(fused + 64 * 512);  // 32768 shorts
    short* aF2   = aF1 + 32768;
    short* aF3   = aF2 + 32768;

    pool_kernel<<<128, 256, 0, stream>>>(vision, audio, pvT, paT);
    mlp1_kernel<<<128, 512, 0, stream>>>(pvT, paT, vw1, vb1, aw1, ab1, h1vT, h1aT);
    mlp2_kernel<<<128, 512, 0, stream>>>(h1vT, h1aT, vw2, vb2, aw2, ab2, aT, bT);
    aprep_kernel<<<16, 256, 0, stream>>>(aT, aF1, aF2, aF3);
    bilinear_kernel<<<1024, 512, 0, stream>>>(fw1, fb1, aT, bT, aF1, aF2, aF3, hbufT);
    fuse2_kernel<<<32, 512, 0, stream>>>(hbufT, fw2, fb2, fused);
    lif_kernel<<<4, 256, 0, stream>>>(fused, out);
}

// Round 11
// 417.705 us; speedup vs baseline: 1.6229x; 1.0472x over previous
//
#include <hip/hip_runtime.h>

#define AB 513
#define TD 263169  // 513*513

typedef float f4 __attribute__((ext_vector_type(4)));
typedef float f32x4 __attribute__((ext_vector_type(4)));
typedef short bf16x8 __attribute__((ext_vector_type(8)));
typedef int i32x4 __attribute__((ext_vector_type(4)));
#define GAS __attribute__((address_space(1)))
#define LAS __attribute__((address_space(3)))

// ---------------------------------------------------------------------------
// Kernel 1a: pool over S. Blocks 0..63 = vision bt, 64..127 = audio bt.
// ---------------------------------------------------------------------------
__global__ __launch_bounds__(256) void pool_kernel(
    const float* __restrict__ vx, const float* __restrict__ ax,
    float* __restrict__ pvT, float* __restrict__ paT)
{
    const int isA = (blockIdx.x >= 64);
    const int bt = blockIdx.x & 63;
    const float* x = isA ? ax : vx;
    float* pT = isA ? paT : pvT;
    const int D = isA ? 512 : 768;
    const int nd4 = D >> 2;
    const int tid = threadIdx.x;
    if (tid < nd4) {
        f4 s0 = {0.f, 0.f, 0.f, 0.f}, s1 = s0, s2 = s0, s3 = s0;
        const float* xp = x + (size_t)bt * 64 * D + tid * 4;
        #pragma unroll 4
        for (int ss = 0; ss < 64; ss += 4) {
            s0 += *(const f4*)(xp + (size_t)ss * D);
            s1 += *(const f4*)(xp + (size_t)(ss + 1) * D);
            s2 += *(const f4*)(xp + (size_t)(ss + 2) * D);
            s3 += *(const f4*)(xp + (size_t)(ss + 3) * D);
        }
        const f4 s = ((s0 + s1) + (s2 + s3)) * 0.015625f;
        #pragma unroll
        for (int q = 0; q < 4; ++q) pT[(tid * 4 + q) * 64 + bt] = s[q];
    }
}

// ---------------------------------------------------------------------------
// Kernel 1b: layer1, weight-stationary. Block = 8-h tile; wave = h row.
// ---------------------------------------------------------------------------
__global__ __launch_bounds__(512) void mlp1_kernel(
    const float* __restrict__ pvT, const float* __restrict__ paT,
    const float* __restrict__ vw1, const float* __restrict__ vb1,
    const float* __restrict__ aw1, const float* __restrict__ ab1,
    float* __restrict__ h1vT, float* __restrict__ h1aT)
{
    const int isA = (blockIdx.x >= 64);
    const int D = isA ? 512 : 768;
    const float* pT = isA ? paT : pvT;
    const float* w1 = isA ? aw1 : vw1;
    const float* b1 = isA ? ab1 : vb1;
    float* h1T = isA ? h1aT : h1vT;
    const int tid = threadIdx.x, lane = tid & 63, w = tid >> 6;
    const int h = (blockIdx.x & 63) * 8 + w;
    const float* wr = w1 + (size_t)h * D;

    float a0 = 0.f, a1 = 0.f, a2 = 0.f, a3 = 0.f;
    for (int d = 0; d < D; d += 16) {
        const f4 w0 = *(const f4*)(wr + d);
        const f4 w1v = *(const f4*)(wr + d + 4);
        const f4 w2v = *(const f4*)(wr + d + 8);
        const f4 w3v = *(const f4*)(wr + d + 12);
        #pragma unroll
        for (int q = 0; q < 4; ++q) {
            a0 = fmaf(w0[q],  pT[(d + q) * 64 + lane], a0);
            a1 = fmaf(w1v[q], pT[(d + 4 + q) * 64 + lane], a1);
            a2 = fmaf(w2v[q], pT[(d + 8 + q) * 64 + lane], a2);
            a3 = fmaf(w3v[q], pT[(d + 12 + q) * 64 + lane], a3);
        }
    }
    h1T[h * 64 + lane] = fmaxf((a0 + a1) + (a2 + a3) + b1[h], 0.f);
}

// ---------------------------------------------------------------------------
// Kernel 1c: layer2 (no relu) + trailing ones row.
// ---------------------------------------------------------------------------
__global__ __launch_bounds__(512) void mlp2_kernel(
    const float* __restrict__ h1vT, const float* __restrict__ h1aT,
    const float* __restrict__ vw2, const float* __restrict__ vb2,
    const float* __restrict__ aw2, const float* __restrict__ ab2,
    float* __restrict__ aTout, float* __restrict__ bTout)
{
    const int isA = (blockIdx.x >= 64);
    const float* hT = isA ? h1aT : h1vT;
    const float* w2 = isA ? aw2 : vw2;
    const float* b2 = isA ? ab2 : vb2;
    float* outT = isA ? bTout : aTout;
    const int tid = threadIdx.x, lane = tid & 63, w = tid >> 6;
    const int h = (blockIdx.x & 63) * 8 + w;
    const float* wr = w2 + (size_t)h * 512;

    float a0 = 0.f, a1 = 0.f, a2 = 0.f, a3 = 0.f;
    for (int d = 0; d < 512; d += 16) {
        const f4 w0 = *(const f4*)(wr + d);
        const f4 w1v = *(const f4*)(wr + d + 4);
        const f4 w2v = *(const f4*)(wr + d + 8);
        const f4 w3v = *(const f4*)(wr + d + 12);
        #pragma unroll
        for (int q = 0; q < 4; ++q) {
            a0 = fmaf(w0[q],  hT[(d + q) * 64 + lane], a0);
            a1 = fmaf(w1v[q], hT[(d + 4 + q) * 64 + lane], a1);
            a2 = fmaf(w2v[q], hT[(d + 8 + q) * 64 + lane], a2);
            a3 = fmaf(w3v[q], hT[(d + 12 + q) * 64 + lane], a3);
        }
    }
    outT[h * 64 + lane] = (a0 + a1) + (a2 + a3) + b2[h];
    if ((blockIdx.x & 63) == 0 && tid < 64) outT[512 * 64 + tid] = 1.0f;
}

// ---------------------------------------------------------------------------
// Kernel 1d: split aT into 3 truncated-bf16 levels in MFMA A-fragment order.
// ---------------------------------------------------------------------------
__global__ __launch_bounds__(256) void aprep_kernel(
    const float* __restrict__ aT,   // (513, 64)
    short* __restrict__ aF1, short* __restrict__ aF2, short* __restrict__ aF3)
{
    const int t = blockIdx.x * 256 + threadIdx.x;  // [0, 4096)
    const int l = t & 63, mt = (t >> 6) & 3, kt = t >> 8;
    const int m = mt * 16 + (l & 15);
    const int kbase = kt * 32 + ((l >> 4) << 3);
    const int obase = ((kt * 4 + mt) * 64 + l) * 8;
    #pragma unroll
    for (int i = 0; i < 8; ++i) {
        const float v = aT[(size_t)(kbase + i) * 64 + m];
        const unsigned u = __float_as_uint(v);
        const float r1 = v - __uint_as_float(u & 0xFFFF0000u);
        const unsigned u1 = __float_as_uint(r1);
        const float r2 = r1 - __uint_as_float(u1 & 0xFFFF0000u);
        const unsigned u2 = __float_as_uint(r2);
        aF1[obase + i] = (short)(u >> 16);
        aF2[obase + i] = (short)(u1 >> 16);
        aF3[obase + i] = (short)(u2 >> 16);
    }
}

// ---------------------------------------------------------------------------
// Kernel 2: bilinear via bf16-split MFMA (R10 math, verified absmax 0).
// NEW: A-fragment REGISTER PREFETCH with explicit vmcnt choreography.
// Per iter kt: wait vmcnt(8)  [drains chunk kt + A(kt); stage(kt+1) stays
// in flight] -> issue A(kt+1) loads (land under compute) -> compute(kt)
// -> STAGE(kt+2) (after compute: no ring race, ring stays 2-deep).
// The old order made the compiler's A-load waits drain the staged chunk
// every iteration (vmcnt is FIFO) -> serialized HBM/compute. kt-loop is
// manually 2x-unrolled with named Aa/Ab register sets (rule #20); kt=14,15
// peeled (15 waits vmcnt(0)).
// ---------------------------------------------------------------------------
__global__ __launch_bounds__(512, 1) void bilinear_kernel(
    const float* __restrict__ fw1,  // (1024, 263169)
    const float* __restrict__ fb1,  // (1024)
    const float* __restrict__ aT,   // (513, 64)
    const float* __restrict__ bT,   // (513, 64)
    const short* __restrict__ aF1, const short* __restrict__ aF2,
    const short* __restrict__ aF3,
    float* __restrict__ hbufT)      // (1024, 64)
{
    __shared__ float ring[8][2][2048];  // 128 KB
    const int tid = threadIdx.x;
    const int l = tid & 63, w = tid >> 6;
    const int o = blockIdx.x;
    const float* __restrict__ W = fw1 + (size_t)o * TD;
    const int we0 = w * 64;
    const int lq = l >> 4, ln = l & 15;
    float* const myring = &ring[w][0][0];

    #define STAGE(buf_, kt_)                                                   \
        do {                                                                   \
            _Pragma("unroll")                                                  \
            for (int is_ = 0; is_ < 8; ++is_) {                                \
                const int g_ = is_ * 64 + l;                                   \
                const int row_ = g_ >> 4, c4_ = (g_ & 15) * 4;                 \
                __builtin_amdgcn_global_load_lds(                              \
                    (const GAS unsigned*)(const void*)(W + (size_t)((kt_) * 32 + row_) * AB + we0 + c4_), \
                    (LAS unsigned*)(void*)(myring + (buf_) * 2048 + is_ * 256 + l * 4), 16, 0, 0); \
            }                                                                  \
        } while (0)

    #define LOADA(A1r, A2r, A3r, kt_)                                          \
        do {                                                                   \
            _Pragma("unroll")                                                  \
            for (int mt_ = 0; mt_ < 4; ++mt_) {                                \
                const int fb_ = (((kt_) * 4 + mt_) * 64 + l) * 8;              \
                A1r[mt_] = *(const bf16x8*)(aF1 + fb_);                        \
                A2r[mt_] = *(const bf16x8*)(aF2 + fb_);                        \
                A3r[mt_] = *(const bf16x8*)(aF3 + fb_);                        \
            }                                                                  \
        } while (0)

    #define COMPUTE(kt_, A1r, A2r, A3r)                                        \
        do {                                                                   \
            const float* __restrict__ wb_ = myring + ((kt_) & 1) * 2048;       \
            _Pragma("unroll")                                                  \
            for (int nt = 0; nt < 4; ++nt) {                                   \
                unsigned u0[8], u1[8], u2[8];                                  \
                _Pragma("unroll")                                              \
                for (int i = 0; i < 8; ++i) {                                  \
                    const float v = wb_[(lq * 8 + i) * 64 + nt * 16 + ln];     \
                    u0[i] = __float_as_uint(v);                                \
                    const float r1 = v - __uint_as_float(u0[i] & 0xFFFF0000u); \
                    u1[i] = __float_as_uint(r1);                               \
                    const float r2 = r1 - __uint_as_float(u1[i] & 0xFFFF0000u);\
                    u2[i] = __float_as_uint(r2);                               \
                }                                                              \
                i32x4 p1, p2, p3;                                              \
                _Pragma("unroll")                                              \
                for (int j = 0; j < 4; ++j) {                                  \
                    p1[j] = (int)((u0[2 * j + 1] & 0xFFFF0000u) | (u0[2 * j] >> 16)); \
                    p2[j] = (int)((u1[2 * j + 1] & 0xFFFF0000u) | (u1[2 * j] >> 16)); \
                    p3[j] = (int)((u2[2 * j + 1] & 0xFFFF0000u) | (u2[2 * j] >> 16)); \
                }                                                              \
                const bf16x8 B1 = __builtin_bit_cast(bf16x8, p1);              \
                const bf16x8 B2 = __builtin_bit_cast(bf16x8, p2);              \
                const bf16x8 B3 = __builtin_bit_cast(bf16x8, p3);              \
                _Pragma("unroll")                                              \
                for (int mt = 0; mt < 4; ++mt) {                               \
                    acc[mt][nt] = __builtin_amdgcn_mfma_f32_16x16x32_bf16(A1r[mt], B1, acc[mt][nt], 0, 0, 0); \
                    acc[mt][nt] = __builtin_amdgcn_mfma_f32_16x16x32_bf16(A1r[mt], B2, acc[mt][nt], 0, 0, 0); \
                    acc[mt][nt] = __builtin_amdgcn_mfma_f32_16x16x32_bf16(A2r[mt], B1, acc[mt][nt], 0, 0, 0); \
                    acc[mt][nt] = __builtin_amdgcn_mfma_f32_16x16x32_bf16(A2r[mt], B2, acc[mt][nt], 0, 0, 0); \
                    acc[mt][nt] = __builtin_amdgcn_mfma_f32_16x16x32_bf16(A1r[mt], B3, acc[mt][nt], 0, 0, 0); \
                    acc[mt][nt] = __builtin_amdgcn_mfma_f32_16x16x32_bf16(A3r[mt], B1, acc[mt][nt], 0, 0, 0); \
                }                                                              \
            }                                                                  \
        } while (0)

    f32x4 acc[4][4];
    #pragma unroll
    for (int mt = 0; mt < 4; ++mt)
        #pragma unroll
        for (int nt = 0; nt < 4; ++nt)
            acc[mt][nt] = (f32x4){0.f, 0.f, 0.f, 0.f};

    bf16x8 Aa1[4], Aa2[4], Aa3[4], Ab1[4], Ab2[4], Ab3[4];

    // prologue: stage(0), A(0), stage(1)  ->  iter-0 wait vmcnt(8) drains
    // stage(0)+A(0), leaves stage(1) in flight.
    STAGE(0, 0);
    LOADA(Aa1, Aa2, Aa3, 0);
    STAGE(1, 1);

    #pragma unroll 1
    for (int it = 0; it < 7; ++it) {        // kt = 2it, 2it+1  (0..13)
        const int kt = 2 * it;
        asm volatile("s_waitcnt vmcnt(8)" ::: "memory");
        LOADA(Ab1, Ab2, Ab3, kt + 1);
        COMPUTE(kt, Aa1, Aa2, Aa3);
        asm volatile("" ::: "memory");      // ds_reads stay above refill DMA
        STAGE(kt & 1, kt + 2);

        asm volatile("s_waitcnt vmcnt(8)" ::: "memory");
        LOADA(Aa1, Aa2, Aa3, kt + 2);
        COMPUTE(kt + 1, Ab1, Ab2, Ab3);
        asm volatile("" ::: "memory");
        STAGE((kt + 1) & 1, kt + 3);
    }
    // kt = 14 (Aa): load A(15) -> Ab; no stage(16)
    asm volatile("s_waitcnt vmcnt(8)" ::: "memory");
    LOADA(Ab1, Ab2, Ab3, 15);
    COMPUTE(14, Aa1, Aa2, Aa3);
    // kt = 15 (Ab): full drain
    asm volatile("s_waitcnt vmcnt(0)" ::: "memory");
    COMPUTE(15, Ab1, Ab2, Ab3);
    // no DMA in flight -> ring reusable as red[].

    // y[bt] = sum_e P[bt,e] * b[e,bt] over this wave's e-range.
    // P fragment: bt = mt*16 + lq*4 + r, e = we0 + nt*16 + ln.
    float ysum[4][4];
    #pragma unroll
    for (int mt = 0; mt < 4; ++mt)
        #pragma unroll
        for (int r = 0; r < 4; ++r) ysum[mt][r] = 0.f;
    #pragma unroll
    for (int mt = 0; mt < 4; ++mt) {
        const int bt0 = mt * 16 + lq * 4;
        #pragma unroll
        for (int nt = 0; nt < 4; ++nt) {
            const int e = we0 + nt * 16 + ln;
            const f4 bv = *(const f4*)(bT + (size_t)e * 64 + bt0);
            #pragma unroll
            for (int r = 0; r < 4; ++r)
                ysum[mt][r] = fmaf(acc[mt][nt][r], bv[r], ysum[mt][r]);
        }
    }
    #pragma unroll
    for (int mt = 0; mt < 4; ++mt)
        #pragma unroll
        for (int r = 0; r < 4; ++r) {
            float v = ysum[mt][r];
            v += __shfl_xor(v, 1, 64);
            v += __shfl_xor(v, 2, 64);
            v += __shfl_xor(v, 4, 64);
            v += __shfl_xor(v, 8, 64);
            ysum[mt][r] = v;
        }
    if (ln == 0) {
        #pragma unroll
        for (int mt = 0; mt < 4; ++mt)
            #pragma unroll
            for (int r = 0; r < 4; ++r)
                myring[mt * 16 + lq * 4 + r] = ysum[mt][r];  // red_main
    }

    // aux: e=512 col (b==1) + d=512 row (a==1), wave's 64-range; lane = bt
    {
        float s0 = 0.f, s1 = 0.f, s2 = 0.f, s3 = 0.f;
        #pragma unroll 4
        for (int k = 0; k < 64; k += 4) {
            s0 = fmaf(aT[(size_t)(we0 + k) * 64 + l], W[(size_t)(we0 + k) * AB + 512], s0);
            s1 = fmaf(aT[(size_t)(we0 + k + 1) * 64 + l], W[(size_t)(we0 + k + 1) * AB + 512], s1);
            s2 = fmaf(aT[(size_t)(we0 + k + 2) * 64 + l], W[(size_t)(we0 + k + 2) * AB + 512], s2);
            s3 = fmaf(aT[(size_t)(we0 + k + 3) * 64 + l], W[(size_t)(we0 + k + 3) * AB + 512], s3);
        }
        #pragma unroll 4
        for (int k = 0; k < 64; k += 4) {
            s0 = fmaf(W[(size_t)512 * AB + we0 + k], bT[(size_t)(we0 + k) * 64 + l], s0);
            s1 = fmaf(W[(size_t)512 * AB + we0 + k + 1], bT[(size_t)(we0 + k + 1) * 64 + l], s1);
            s2 = fmaf(W[(size_t)512 * AB + we0 + k + 2], bT[(size_t)(we0 + k + 2) * 64 + l], s2);
            s3 = fmaf(W[(size_t)512 * AB + we0 + k + 3], bT[(size_t)(we0 + k + 3) * 64 + l], s3);
        }
        myring[64 + l] = (s0 + s1) + (s2 + s3);  // red_aux
    }

    __syncthreads();

    if (w == 0) {
        float t2 = 0.f;
        #pragma unroll
        for (int k = 0; k < 8; ++k)
            t2 += ring[k][0][l] + ring[k][0][64 + l];
        t2 += W[(size_t)512 * AB + 512] + fb1[o];  // corner (a=b=1)
        hbufT[(size_t)o * 64 + l] = fmaxf(t2, 0.f);
    }
    #undef STAGE
    #undef LOADA
    #undef COMPUTE
}

// ---------------------------------------------------------------------------
// Kernel 3a: fused[bt, f] = h[bt, :] @ fw2[f, :] + fb2[f].
// ---------------------------------------------------------------------------
__global__ __launch_bounds__(512) void fuse2_kernel(
    const float* __restrict__ hbufT,  // (1024, 64)
    const float* __restrict__ fw2,    // (512, 1024)
    const float* __restrict__ fb2,    // (512)
    float* __restrict__ fused)        // (64, 512)
{
    const int tid = threadIdx.x, lane = tid & 63, w = tid >> 6;
    #pragma unroll
    for (int k = 0; k < 2; ++k) {
        const int f = blockIdx.x * 16 + w * 2 + k;
        const float* wr = fw2 + (size_t)f * 1024;
        float a0 = 0.f, a1 = 0.f, a2 = 0.f, a3 = 0.f;
        for (int o = 0; o < 1024; o += 16) {
            const f4 w0 = *(const f4*)(wr + o);
            const f4 w1v = *(const f4*)(wr + o + 4);
            const f4 w2v = *(const f4*)(wr + o + 8);
            const f4 w3v = *(const f4*)(wr + o + 12);
            #pragma unroll
            for (int q = 0; q < 4; ++q) {
                a0 = fmaf(w0[q],  hbufT[(o + q) * 64 + lane], a0);
                a1 = fmaf(w1v[q], hbufT[(o + 4 + q) * 64 + lane], a1);
                a2 = fmaf(w2v[q], hbufT[(o + 8 + q) * 64 + lane], a2);
                a3 = fmaf(w3v[q], hbufT[(o + 12 + q) * 64 + lane], a3);
            }
        }
        fused[lane * 512 + f] = (a0 + a1) + (a2 + a3) + fb2[f];
    }
}

// ---------------------------------------------------------------------------
// Kernel 3b: LIF over time. 1024 independent (b, d) chains, T = 32.
// ---------------------------------------------------------------------------
__global__ __launch_bounds__(256) void lif_kernel(
    const float* __restrict__ fused,  // (2, 32, 512)
    float* __restrict__ out)          // (2, 32, 512)
{
    const int idx = blockIdx.x * 256 + threadIdx.x;
    if (idx >= 1024) return;
    const int b = idx >> 9, dd = idx & 511;
    float mem = 0.f;
    for (int t = 0; t < 32; ++t) {
        const size_t off = ((size_t)(b * 32 + t) * 512) + dd;
        mem = 0.9f * mem + fused[off];
        const float s = (mem >= 1.0f) ? 1.0f : 0.0f;
        out[off] = s;
        mem -= s;
    }
}

// ---------------------------------------------------------------------------
extern "C" void kernel_launch(void* const* d_in, const int* in_sizes, int n_in,
                              void* d_out, int out_size, void* d_ws, size_t ws_size,
                              hipStream_t stream) {
    const float* vision = (const float*)d_in[0];
    const float* audio  = (const float*)d_in[1];
    const float* vw1 = (const float*)d_in[2];
    const float* vb1 = (const float*)d_in[3];
    const float* vw2 = (const float*)d_in[4];
    const float* vb2 = (const float*)d_in[5];
    const float* aw1 = (const float*)d_in[6];
    const float* ab1 = (const float*)d_in[7];
    const float* aw2 = (const float*)d_in[8];
    const float* ab2 = (const float*)d_in[9];
    const float* fw1 = (const float*)d_in[10];
    const float* fb1 = (const float*)d_in[11];
    const float* fw2 = (const float*)d_in[12];
    const float* fb2 = (const float*)d_in[13];
    float* out = (float*)d_out;

    float* ws    = (float*)d_ws;
    float* pvT   = ws;                  // 768*64
    float* paT   = pvT + 768 * 64;      // 512*64
    float* h1vT  = paT + 512 * 64;      // 512*64
    float* h1aT  = h1vT + 512 * 64;     // 512*64
    float* aT    = h1aT + 512 * 64;     // 513*64
    float* bT    = aT + AB * 64;        // 513*64
    float* hbufT = bT + AB * 64;        // 1024*64
    float* fused = hbufT + 1024 * 64;   // 64*512
    short* aF1   = (short*)(fused + 64 * 512);  // 32768 shorts
    short* aF2   = aF1 + 32768;
    short* aF3   = aF2 + 32768;

    pool_kernel<<<128, 256, 0, stream>>>(vision, audio, pvT, paT);
    mlp1_kernel<<<128, 512, 0, stream>>>(pvT, paT, vw1, vb1, aw1, ab1, h1vT, h1aT);
    mlp2_kernel<<<128, 512, 0, stream>>>(h1vT, h1aT, vw2, vb2, aw2, ab2, aT, bT);
    aprep_kernel<<<16, 256, 0, stream>>>(aT, aF1, aF2, aF3);
    bilinear_kernel<<<1024, 512, 0, stream>>>(fw1, fb1, aT, bT, aF1, aF2, aF3, hbufT);
    fuse2_kernel<<<32, 512, 0, stream>>>(hbufT, fw2, fb2, fused);
    lif_kernel<<<4, 256, 0, stream>>>(fused, out);
}